// Round 4
// baseline (385.754 us; speedup 1.0000x reference)
//
#include <hip/hip_runtime.h>

#define BB 16
#define CC 256
#define NN 1024

typedef _Float16 f16;
typedef __attribute__((ext_vector_type(8))) _Float16 half8;   // MFMA A/B frag (4 VGPRs)
typedef __attribute__((ext_vector_type(4))) _Float16 half4_t; // 8-byte f16 store
typedef __attribute__((ext_vector_type(4))) float f32x4;      // MFMA C/D frag

__device__ __forceinline__ half8 ldg8(const f16* p) {
  return *reinterpret_cast<const half8*>(p);
}

// ---------------- weight transpose + f16 hi/lo split: W fp32 [ci][co] -> WThi/WTlo f16 [co][ci] ----
struct WT5 {
  const float* s[5];
  f16* dhi[5];
  f16* dlo[5];
};

__global__ void __launch_bounds__(256) k_transposeW(WT5 p) {
  __shared__ float tile[64][65];
  const float* s = p.s[blockIdx.z];
  f16* dhi = p.dhi[blockIdx.z];
  f16* dlo = p.dlo[blockIdx.z];
  int r0 = blockIdx.y * 64, c0 = blockIdx.x * 64;
  int tid = threadIdx.x;
  for (int e = tid; e < 64 * 16; e += 256) {
    int r = e >> 4, c4 = (e & 15) << 2;
    float4 u = *reinterpret_cast<const float4*>(s + (size_t)(r0 + r) * 256 + c0 + c4);
    tile[r][c4 + 0] = u.x; tile[r][c4 + 1] = u.y;
    tile[r][c4 + 2] = u.z; tile[r][c4 + 3] = u.w;
  }
  __syncthreads();
  for (int e = tid; e < 64 * 16; e += 256) {
    int c = e >> 4, r4 = (e & 15) << 2;
    half4_t vh, vl;
#pragma unroll
    for (int i = 0; i < 4; ++i) {
      float v = tile[r4 + i][c];
      f16 h = (f16)v;
      vh[i] = h;
      vl[i] = (f16)(v - (float)h);
    }
    size_t o = (size_t)(c0 + c) * 256 + r0 + r4;
    *reinterpret_cast<half4_t*>(dhi + o) = vh;
    *reinterpret_cast<half4_t*>(dlo + o) = vl;
  }
}

// ---------------- QKV: x fp32 [bg][c][n] -> qhi [bl][n][c], khi/klo [bl][n][c], vThi [bl][c][n] ----
// grid (N/64, nb), block 256 (4 waves, 16 n-rows each)
__global__ void __launch_bounds__(256) k_qkv(const float* __restrict__ x,
    const f16* __restrict__ wqThi,
    const f16* __restrict__ wkThi, const f16* __restrict__ wkTlo,
    const f16* __restrict__ wvThi,
    const float* __restrict__ bq, const float* __restrict__ bk, const float* __restrict__ bv,
    f16* __restrict__ qhi, f16* __restrict__ khi, f16* __restrict__ klo,
    f16* __restrict__ vThi, int b_base) {
  __shared__ f16 Tshi[64][264];
  __shared__ f16 Tslo[64][264];
  int bl = blockIdx.y, bg = b_base + bl, n0 = blockIdx.x * 64;
  int tid = threadIdx.x, wave = tid >> 6, lane = tid & 63;
  int row16 = lane & 15, quad = lane >> 4;

  // stage x[bg, :, n0:n0+64] transposed, split hi/lo
  for (int e = tid; e < 256 * 16; e += 256) {
    int c = e >> 4, n4 = (e & 15) << 2;
    float4 u = *reinterpret_cast<const float4*>(x + (size_t)(bg * CC + c) * NN + n0 + n4);
    float uv[4] = {u.x, u.y, u.z, u.w};
#pragma unroll
    for (int i = 0; i < 4; ++i) {
      f16 h = (f16)uv[i];
      Tshi[n4 + i][c] = h;
      Tslo[n4 + i][c] = (f16)(uv[i] - (float)h);
    }
  }
  __syncthreads();

  // A-frags: 16 rows per wave, K=256 (8 frags), hi + lo
  half8 ah[8], al[8];
#pragma unroll
  for (int kc = 0; kc < 8; ++kc) {
    ah[kc] = *reinterpret_cast<const half8*>(&Tshi[wave * 16 + row16][kc * 32 + quad * 8]);
    al[kc] = *reinterpret_cast<const half8*>(&Tslo[wave * 16 + row16][kc * 32 + quad * 8]);
  }

  // ---- q: 2-term (x_full * wq_hi), stored hi only ----
#pragma unroll
  for (int ct = 0; ct < 16; ++ct) {
    f32x4 acc = {0.f, 0.f, 0.f, 0.f};
    const f16* bh = wqThi + (size_t)(ct * 16 + row16) * CC + quad * 8;
#pragma unroll
    for (int kc = 0; kc < 8; ++kc) {
      half8 b = ldg8(bh + kc * 32);
      acc = __builtin_amdgcn_mfma_f32_16x16x32_f16(ah[kc], b, acc, 0, 0, 0);
      acc = __builtin_amdgcn_mfma_f32_16x16x32_f16(al[kc], b, acc, 0, 0, 0);
    }
    int co = ct * 16 + row16;
    float bb = bq[co];
#pragma unroll
    for (int r = 0; r < 4; ++r) {
      int orow = wave * 16 + quad * 4 + r;
      qhi[(size_t)(bl * NN + n0 + orow) * CC + co] = (f16)(acc[r] + bb);
    }
  }

  // ---- k: 3-term (x_full * wk_full), stored hi+lo ----
#pragma unroll
  for (int ct = 0; ct < 16; ++ct) {
    f32x4 acc = {0.f, 0.f, 0.f, 0.f};
    const f16* bh = wkThi + (size_t)(ct * 16 + row16) * CC + quad * 8;
    const f16* blp = wkTlo + (size_t)(ct * 16 + row16) * CC + quad * 8;
#pragma unroll
    for (int kc = 0; kc < 8; ++kc) {
      half8 b = ldg8(bh + kc * 32);
      half8 bl2 = ldg8(blp + kc * 32);
      acc = __builtin_amdgcn_mfma_f32_16x16x32_f16(ah[kc], b, acc, 0, 0, 0);
      acc = __builtin_amdgcn_mfma_f32_16x16x32_f16(al[kc], b, acc, 0, 0, 0);
      acc = __builtin_amdgcn_mfma_f32_16x16x32_f16(ah[kc], bl2, acc, 0, 0, 0);
    }
    int co = ct * 16 + row16;
    float bb = bk[co];
#pragma unroll
    for (int r = 0; r < 4; ++r) {
      int orow = wave * 16 + quad * 4 + r;
      float v = acc[r] + bb;
      f16 h = (f16)v;
      size_t idx = (size_t)(bl * NN + n0 + orow) * CC + co;
      khi[idx] = h;
      klo[idx] = (f16)(v - (float)h);
    }
  }

  // ---- v: 2-term, written transposed vThi[bl][co][n] ----
#pragma unroll
  for (int ct = 0; ct < 16; ++ct) {
    f32x4 acc = {0.f, 0.f, 0.f, 0.f};
    const f16* bh = wvThi + (size_t)(ct * 16 + row16) * CC + quad * 8;
#pragma unroll
    for (int kc = 0; kc < 8; ++kc) {
      half8 b = ldg8(bh + kc * 32);
      acc = __builtin_amdgcn_mfma_f32_16x16x32_f16(ah[kc], b, acc, 0, 0, 0);
      acc = __builtin_amdgcn_mfma_f32_16x16x32_f16(al[kc], b, acc, 0, 0, 0);
    }
    int co = ct * 16 + row16;
    float bb = bv[co];
    half4_t o;
#pragma unroll
    for (int r = 0; r < 4; ++r) o[r] = (f16)(acc[r] + bb);
    *reinterpret_cast<half4_t*>(vThi + (size_t)(bl * CC + co) * NN + n0 + wave * 16 + quad * 4) = o;
  }
}

// ---------------- fused flash attention (swapped roles) + MLP(SiLU) + LayerNorm ----------------
// out[bg,j,c] = LN(MLP(sum_i softmax_i(k_j . q_i) * v[i,c]))   ; output written [bg][c][j]
struct SmemA {
  f16 Ks[32][264];      // q-proj rows i (hi) — B operand of scores
  f16 Vts[256][40];     // vT tile [c][i] (hi) — B operand of PV
  f16 Pw[4][16][40];    // per-wave P (C->A layout round-trip)
};
struct SmemB {
  union {
    f16 e16[4][16][264];   // f16 exchange (att, h)
    float ef[4][16][132];  // fp32 exchange for output store
  };
};
union Smem {
  SmemA a;
  SmemB b_;
};

__global__ void __launch_bounds__(256) k_attn_mlp(
    const f16* __restrict__ qhi,
    const f16* __restrict__ khi, const f16* __restrict__ klo,
    const f16* __restrict__ vThi,
    const f16* __restrict__ w1Thi, const float* __restrict__ b1,
    const f16* __restrict__ w2Thi, const float* __restrict__ b2,
    const float* __restrict__ gamma, const float* __restrict__ beta,
    float* __restrict__ out, int b_base) {
  __shared__ Smem sm;
  int bl = blockIdx.y, bg = b_base + bl;
  int j0 = blockIdx.x * 64;
  int tid = threadIdx.x, wave = tid >> 6, lane = tid & 63;
  int row16 = lane & 15, quad = lane >> 4;

  // A-frags: k-proj rows j (hi + lo), K=256
  const f16* krow = khi + (size_t)(bl * NN + j0 + wave * 16 + row16) * CC + quad * 8;
  const f16* krol = klo + (size_t)(bl * NN + j0 + wave * 16 + row16) * CC + quad * 8;
  half8 kfh[8], kfl[8];
#pragma unroll
  for (int kc = 0; kc < 8; ++kc) {
    kfh[kc] = ldg8(krow + kc * 32);
    kfl[kc] = ldg8(krol + kc * 32);
  }

  f32x4 O[16];
#pragma unroll
  for (int ct = 0; ct < 16; ++ct) O[ct] = {0.f, 0.f, 0.f, 0.f};
  float m_run[4], l_run[4];
#pragma unroll
  for (int r = 0; r < 4; ++r) { m_run[r] = -1e30f; l_run[r] = 0.f; }

  for (int it = 0; it < 32; ++it) {
    int i0 = it * 32;
    __syncthreads();  // prior iteration's LDS reads complete
    // stage q-proj tile (hi): 32 x 256
    for (int e = tid; e < 2048; e += 256) {
      int i = e >> 6, c4 = (e & 63) << 2;
      *reinterpret_cast<half4_t*>(&sm.a.Ks[i][c4]) =
          *reinterpret_cast<const half4_t*>(qhi + (size_t)(bl * NN + i0 + i) * CC + c4);
    }
    // stage vT tile (hi): 256 x 32
    for (int e = tid; e < 2048; e += 256) {
      int c = e >> 3, i4 = (e & 7) << 2;
      *reinterpret_cast<half4_t*>(&sm.a.Vts[c][i4]) =
          *reinterpret_cast<const half4_t*>(vThi + (size_t)(bl * CC + c) * NN + i0 + i4);
    }
    __syncthreads();

    // scores S[16 j][32 i]: 2-term (k_hi + k_lo) * q_hi
    f32x4 s0 = {0.f, 0.f, 0.f, 0.f}, s1 = {0.f, 0.f, 0.f, 0.f};
#pragma unroll
    for (int kc = 0; kc < 8; ++kc) {
      half8 b0 = *reinterpret_cast<const half8*>(&sm.a.Ks[row16][kc * 32 + quad * 8]);
      half8 b1v = *reinterpret_cast<const half8*>(&sm.a.Ks[16 + row16][kc * 32 + quad * 8]);
      s0 = __builtin_amdgcn_mfma_f32_16x16x32_f16(kfh[kc], b0, s0, 0, 0, 0);
      s0 = __builtin_amdgcn_mfma_f32_16x16x32_f16(kfl[kc], b0, s0, 0, 0, 0);
      s1 = __builtin_amdgcn_mfma_f32_16x16x32_f16(kfh[kc], b1v, s1, 0, 0, 0);
      s1 = __builtin_amdgcn_mfma_f32_16x16x32_f16(kfl[kc], b1v, s1, 0, 0, 0);
    }

    // online softmax per j-row
    float alpha[4];
#pragma unroll
    for (int r = 0; r < 4; ++r) {
      float mx = fmaxf(s0[r], s1[r]);
#pragma unroll
      for (int off = 1; off < 16; off <<= 1) mx = fmaxf(mx, __shfl_xor(mx, off, 64));
      float mnew = fmaxf(m_run[r], mx);
      alpha[r] = __expf(m_run[r] - mnew);
      m_run[r] = mnew;
      float p0 = __expf(s0[r] - mnew);
      float p1 = __expf(s1[r] - mnew);
      float sm2 = p0 + p1;
#pragma unroll
      for (int off = 1; off < 16; off <<= 1) sm2 += __shfl_xor(sm2, off, 64);
      l_run[r] = l_run[r] * alpha[r] + sm2;
      sm.a.Pw[wave][quad * 4 + r][row16] = (f16)p0;
      sm.a.Pw[wave][quad * 4 + r][16 + row16] = (f16)p1;
    }
#pragma unroll
    for (int ct = 0; ct < 16; ++ct)
#pragma unroll
      for (int r = 0; r < 4; ++r) O[ct][r] *= alpha[r];

    // PV: O[16 j][256 c] += P[16][32] @ V[32][256]  (Pw same-wave write->read; in-order LDS)
    half8 pf = *reinterpret_cast<const half8*>(&sm.a.Pw[wave][row16][quad * 8]);
#pragma unroll
    for (int ct = 0; ct < 16; ++ct) {
      half8 vf = *reinterpret_cast<const half8*>(&sm.a.Vts[ct * 16 + row16][quad * 8]);
      O[ct] = __builtin_amdgcn_mfma_f32_16x16x32_f16(pf, vf, O[ct], 0, 0, 0);
    }
  }
  __syncthreads();  // all PV reads done before exchange overwrites phase-A LDS

  // ---- phase B: MLP + LN on the 64x256 att tile (rows are wave-private) ----
  float inv[4];
#pragma unroll
  for (int r = 0; r < 4; ++r) inv[r] = 1.f / l_run[r];
#pragma unroll
  for (int ct = 0; ct < 16; ++ct)
#pragma unroll
    for (int r = 0; r < 4; ++r)
      sm.b_.e16[wave][quad * 4 + r][ct * 16 + row16] = (f16)(O[ct][r] * inv[r]);

  half8 af[8];
#pragma unroll
  for (int kc = 0; kc < 8; ++kc)
    af[kc] = *reinterpret_cast<const half8*>(&sm.b_.e16[wave][row16][kc * 32 + quad * 8]);

  // GEMM1: h = silu(att @ w1 + b1) -> e16 (own-wave rows)
#pragma unroll
  for (int ct = 0; ct < 16; ++ct) {
    f32x4 acc = {0.f, 0.f, 0.f, 0.f};
    const f16* brow = w1Thi + (size_t)(ct * 16 + row16) * CC + quad * 8;
#pragma unroll
    for (int kc = 0; kc < 8; ++kc)
      acc = __builtin_amdgcn_mfma_f32_16x16x32_f16(af[kc], ldg8(brow + kc * 32), acc, 0, 0, 0);
    int co = ct * 16 + row16;
    float bb = b1[co];
#pragma unroll
    for (int r = 0; r < 4; ++r) {
      float xg = acc[r] + bb;
      float h = xg / (1.f + __expf(-xg));  // SiLU
      sm.b_.e16[wave][quad * 4 + r][co] = (f16)h;
    }
  }

  half8 hf[8];
#pragma unroll
  for (int kc = 0; kc < 8; ++kc)
    hf[kc] = *reinterpret_cast<const half8*>(&sm.b_.e16[wave][row16][kc * 32 + quad * 8]);

  f32x4 acc2[16];
#pragma unroll
  for (int ct = 0; ct < 16; ++ct) {
    f32x4 acc = {0.f, 0.f, 0.f, 0.f};
    const f16* brow = w2Thi + (size_t)(ct * 16 + row16) * CC + quad * 8;
#pragma unroll
    for (int kc = 0; kc < 8; ++kc)
      acc = __builtin_amdgcn_mfma_f32_16x16x32_f16(hf[kc], ldg8(brow + kc * 32), acc, 0, 0, 0);
    float bb = b2[ct * 16 + row16];
#pragma unroll
    for (int r = 0; r < 4; ++r) acc[r] += bb;
    acc2[ct] = acc;
  }

  // LayerNorm over C (per-row stats via 16-lane butterfly)
  float sum[4] = {0.f, 0.f, 0.f, 0.f}, ssq[4] = {0.f, 0.f, 0.f, 0.f};
#pragma unroll
  for (int ct = 0; ct < 16; ++ct)
#pragma unroll
    for (int r = 0; r < 4; ++r) { float xv = acc2[ct][r]; sum[r] += xv; ssq[r] += xv * xv; }
  float mean[4], rstd[4];
#pragma unroll
  for (int r = 0; r < 4; ++r) {
#pragma unroll
    for (int off = 1; off < 16; off <<= 1) {
      sum[r] += __shfl_xor(sum[r], off, 64);
      ssq[r] += __shfl_xor(ssq[r], off, 64);
    }
    mean[r] = sum[r] * (1.f / 256.f);
    float var = ssq[r] * (1.f / 256.f) - mean[r] * mean[r];
    rstd[r] = rsqrtf(var + 1e-5f);
  }
#pragma unroll
  for (int ct = 0; ct < 16; ++ct) {
    int co = ct * 16 + row16;
    float g = gamma[co], be = beta[co];
#pragma unroll
    for (int r = 0; r < 4; ++r)
      acc2[ct][r] = (acc2[ct][r] - mean[r]) * rstd[r] * g + be;
  }

  // output: out[bg][c][j0+n] fp32, via two half-column passes through fp32 exchange
#pragma unroll
  for (int p = 0; p < 2; ++p) {
    __syncthreads();  // prior exchange reads complete
#pragma unroll
    for (int ct2 = 0; ct2 < 8; ++ct2) {
      int ct = p * 8 + ct2;
      int col = ct2 * 16 + row16;
#pragma unroll
      for (int r = 0; r < 4; ++r)
        sm.b_.ef[wave][quad * 4 + r][col] = acc2[ct][r];
    }
    __syncthreads();
    for (int e = tid; e < 128 * 16; e += 256) {
      int cl = e >> 4, n4 = (e & 15) << 2;
      int w = n4 >> 4, rbase = n4 & 15;
      float4 v;
      v.x = sm.b_.ef[w][rbase + 0][cl];
      v.y = sm.b_.ef[w][rbase + 1][cl];
      v.z = sm.b_.ef[w][rbase + 2][cl];
      v.w = sm.b_.ef[w][rbase + 3][cl];
      *reinterpret_cast<float4*>(out + (size_t)(bg * CC + p * 128 + cl) * NN + j0 + n4) = v;
    }
  }
}

extern "C" void kernel_launch(void* const* d_in, const int* in_sizes, int n_in,
                              void* d_out, int out_size, void* d_ws, size_t ws_size,
                              hipStream_t stream) {
  (void)in_sizes; (void)n_in; (void)out_size;
  const float* x     = (const float*)d_in[0];
  const float* wq    = (const float*)d_in[1];
  const float* bq    = (const float*)d_in[2];
  const float* wk    = (const float*)d_in[3];
  const float* bk    = (const float*)d_in[4];
  const float* wv    = (const float*)d_in[5];
  const float* bv    = (const float*)d_in[6];
  const float* w1    = (const float*)d_in[7];
  const float* b1    = (const float*)d_in[8];
  const float* w2    = (const float*)d_in[9];
  const float* b2    = (const float*)d_in[10];
  const float* gamma = (const float*)d_in[11];
  const float* beta  = (const float*)d_in[12];
  float* out = (float*)d_out;

  // workspace (all f16): [10 weight arrays][q hi][k hi][k lo][vT hi] chunked over batches
  const size_t WE = 65536;               // elems per weight array
  const size_t SB = (size_t)NN * CC;     // 262,144 elems per batch per tensor
  f16* base = (f16*)d_ws;
  f16* wqThi = base + 0 * WE;
  f16* wqTlo = base + 1 * WE;
  f16* wkThi = base + 2 * WE;
  f16* wkTlo = base + 3 * WE;
  f16* wvThi = base + 4 * WE;
  f16* wvTlo = base + 5 * WE;
  f16* w1Thi = base + 6 * WE;
  f16* w1Tlo = base + 7 * WE;
  f16* w2Thi = base + 8 * WE;
  f16* w2Tlo = base + 9 * WE;

  size_t wbytes = 10 * WE * sizeof(f16);           // 1.31 MB
  size_t perb   = 4 * SB * sizeof(f16);            // 2 MB per batch
  int nb = (ws_size > wbytes) ? (int)((ws_size - wbytes) / perb) : 1;
  if (nb < 1) nb = 1;
  if (nb > BB) nb = BB;

  f16* qb  = base + 10 * WE;
  f16* kbh = qb + (size_t)nb * SB;
  f16* kbl = kbh + (size_t)nb * SB;
  f16* vTb = kbl + (size_t)nb * SB;

  WT5 p;
  p.s[0] = wq; p.s[1] = wk; p.s[2] = wv; p.s[3] = w1; p.s[4] = w2;
  p.dhi[0] = wqThi; p.dhi[1] = wkThi; p.dhi[2] = wvThi; p.dhi[3] = w1Thi; p.dhi[4] = w2Thi;
  p.dlo[0] = wqTlo; p.dlo[1] = wkTlo; p.dlo[2] = wvTlo; p.dlo[3] = w1Tlo; p.dlo[4] = w2Tlo;
  k_transposeW<<<dim3(4, 4, 5), 256, 0, stream>>>(p);

  for (int b0 = 0; b0 < BB; b0 += nb) {
    int cb = (b0 + nb <= BB) ? nb : (BB - b0);
    k_qkv<<<dim3(16, cb), 256, 0, stream>>>(x, wqThi, wkThi, wkTlo, wvThi, bq, bk, bv,
                                            qb, kbh, kbl, vTb, b0);
    k_attn_mlp<<<dim3(16, cb), 256, 0, stream>>>(qb, kbh, kbl, vTb, w1Thi, b1, w2Thi, b2,
                                                 gamma, beta, out, b0);
  }
}